// Round 3
// baseline (3846.054 us; speedup 1.0000x reference)
//
#include <hip/hip_runtime.h>
#include <math.h>

#define B_ 16
#define L_ 8192
#define C_ 256
#define KTOP 2457            // max(1, int(8192*0.3))
#define JT 20                // recurrence taps; ||A||^20 ~ 1e-16 -> exact at fp32
#define M1 (B_*L_)           // 131072
#define M2 (B_*KTOP)         // 39312

// workspace layout in floats
#define XP_OFF  ((size_t)0)
#define Y_OFF   (XP_OFF + (size_t)M1*C_)        // 33554432
#define E_OFF   (Y_OFF  + (size_t)M2*C_)        // 43618304
#define CN_OFF  (E_OFF  + (size_t)M1)           // 43749376
#define CF_OFF  (CN_OFF + (size_t)B_*C_)        // 43753472
#define IDX_OFF (CF_OFF + (size_t)JT*C_)        // 43758592 (ints)
#define WIT_OFF (IDX_OFF + (size_t)M2)          // 43797904
#define WOT_OFF (WIT_OFF + (size_t)C_*C_)       // 43863440

// ---------------- transpose Wi/Wo (256x256 each) into [K][N] layout ----------------
__global__ void transpose_kernel(const float* __restrict__ Wi, const float* __restrict__ Wo,
                                 float* __restrict__ WiT, float* __restrict__ WoT)
{
    __shared__ float t[32][33];
    const float* src = blockIdx.z ? Wo : Wi;
    float* dst = blockIdx.z ? WoT : WiT;
    int r0 = blockIdx.y * 32, c0 = blockIdx.x * 32;
    int tx = threadIdx.x, ty = threadIdx.y;      // 32 x 8
    #pragma unroll
    for (int r = 0; r < 4; r++)
        t[ty + r*8][tx] = src[(size_t)(r0 + ty + r*8)*C_ + c0 + tx];
    __syncthreads();
    #pragma unroll
    for (int r = 0; r < 4; r++)
        dst[(size_t)(c0 + ty + r*8)*C_ + r0 + tx] = t[tx][ty + r*8];
}

// ---------------- coef: cf[j][c] = sigmoid(Cp[c,:]) . (A^j sigmoid(Bp)) ----------------
__global__ void coef_kernel(const float* __restrict__ A, const float* __restrict__ Bp,
                            const float* __restrict__ Cp, float* __restrict__ cf)
{
    int c = threadIdx.x;                       // 256 threads
    __shared__ float As[256];
    __shared__ float v0[16];
    As[c] = A[c];
    if (c < 16) v0[c] = 1.0f / (1.0f + expf(-Bp[c]));
    float sC[16];
    #pragma unroll
    for (int i = 0; i < 16; i++) sC[i] = 1.0f / (1.0f + expf(-Cp[c*16 + i]));
    __syncthreads();
    float v[16];
    #pragma unroll
    for (int i = 0; i < 16; i++) v[i] = v0[i];
    for (int j = 0; j < JT; j++) {
        float d = 0.f;
        #pragma unroll
        for (int i = 0; i < 16; i++) d += sC[i] * v[i];
        cf[j*C_ + c] = d;
        float nv[16];
        #pragma unroll
        for (int i = 0; i < 16; i++) {
            float s = 0.f;
            #pragma unroll
            for (int m = 0; m < 16; m++) s += As[i*16 + m] * v[m];
            nv[i] = s;
        }
        #pragma unroll
        for (int i = 0; i < 16; i++) v[i] = nv[i];
    }
}

// ---------------- center2: cn[b,:] = normalize(dyt(x[b,L/2,:]) @ WiT + bi) ----------------
__global__ void center2_kernel(const float* __restrict__ x, const float* __restrict__ WiT,
                               const float* __restrict__ bi, const float* __restrict__ alpha,
                               const float* __restrict__ dw, const float* __restrict__ db,
                               float* __restrict__ cn)
{
    __shared__ float xn[256];
    __shared__ float red[4];
    int b = blockIdx.x, c = threadIdx.x;       // 256 threads
    float al = alpha[0];
    size_t base = ((size_t)b*L_ + L_/2)*C_;
    xn[c] = tanhf(al*x[base + c])*dw[c] + db[c];
    __syncthreads();
    float s = bi[c];
    #pragma unroll 8
    for (int k = 0; k < 256; k++) s = fmaf(xn[k], WiT[(size_t)k*C_ + c], s);
    float ss = s*s;
    #pragma unroll
    for (int off = 32; off; off >>= 1) ss += __shfl_xor(ss, off);
    if ((c & 63) == 0) red[c >> 6] = ss;
    __syncthreads();
    float tot = red[0] + red[1] + red[2] + red[3];
    float inv = 1.0f / fmaxf(sqrtf(tot), 1e-12f);
    cn[b*C_ + c] = s * inv;
}

// ---------------- GEMM1 + fused e: xp = dyt(x)@WiT + bi ; e[m] = xp.cn/||xp|| ----------------
// BM=128, BN=256(full), BK=32, 256 threads, 16x8 micro-tile
// As[128][32] row-major: staging writes contiguous (conflict-free); reads scalar 2-addr broadcast
__global__ __launch_bounds__(256, 3) void gemm1_kernel(
    const float* __restrict__ x, const float* __restrict__ WiT,
    const float* __restrict__ bi, const float* __restrict__ alpha,
    const float* __restrict__ dw, const float* __restrict__ db,
    const float* __restrict__ cn, float* __restrict__ xp, float* __restrict__ e)
{
    __shared__ float As[128*32];   // [m][kk] row-major
    __shared__ float Bs[32*256];   // [kk][n]
    const int tid = threadIdx.x;
    const int tn2 = tid & 31;      // cols tn2*4..+3 and 128+tn2*4..+3
    const int tm2 = tid >> 5;      // rows tm2*16..+15
    const int m0 = blockIdx.x * 128;
    const int b  = m0 >> 13;
    const float al = alpha[0];

    float acc[16][8];
    #pragma unroll
    for (int i = 0; i < 16; i++)
        #pragma unroll
        for (int j = 0; j < 8; j++) acc[i][j] = 0.f;

    for (int k0 = 0; k0 < C_; k0 += 32) {
        // A stage: 128x32 tile, dyt transform, row-major, contiguous writes
        #pragma unroll
        for (int it = 0; it < 4; it++) {
            int idx = tid + it*256;
            int ar = idx >> 3;             // row 0..127
            int ak = (idx & 7) * 4;        // k 0,4,..,28
            float4 v  = *(const float4*)&x[(size_t)(m0 + ar)*C_ + k0 + ak];
            float4 w4 = *(const float4*)&dw[k0 + ak];
            float4 b4 = *(const float4*)&db[k0 + ak];
            float4 o;
            o.x = tanhf(al*v.x)*w4.x + b4.x;
            o.y = tanhf(al*v.y)*w4.y + b4.y;
            o.z = tanhf(al*v.z)*w4.z + b4.z;
            o.w = tanhf(al*v.w)*w4.w + b4.w;
            *(float4*)&As[ar*32 + ak] = o;
        }
        // B stage: row copy (contiguous, conflict-free)
        #pragma unroll
        for (int it = 0; it < 8; it++) {
            int idx = tid + it*256;
            int br = idx >> 6;
            int bc = (idx & 63) * 4;
            *(float4*)&Bs[br*256 + bc] = *(const float4*)&WiT[(size_t)(k0 + br)*C_ + bc];
        }
        __syncthreads();
        #pragma unroll 4
        for (int kk = 0; kk < 32; kk++) {
            float4 b0 = *(const float4*)&Bs[kk*256 + tn2*4];
            float4 b1 = *(const float4*)&Bs[kk*256 + tn2*4 + 128];
            #pragma unroll
            for (int i = 0; i < 16; i++) {
                float a = As[(tm2*16 + i)*32 + kk];
                acc[i][0] = fmaf(a, b0.x, acc[i][0]);
                acc[i][1] = fmaf(a, b0.y, acc[i][1]);
                acc[i][2] = fmaf(a, b0.z, acc[i][2]);
                acc[i][3] = fmaf(a, b0.w, acc[i][3]);
                acc[i][4] = fmaf(a, b1.x, acc[i][4]);
                acc[i][5] = fmaf(a, b1.y, acc[i][5]);
                acc[i][6] = fmaf(a, b1.z, acc[i][6]);
                acc[i][7] = fmaf(a, b1.w, acc[i][7]);
            }
        }
        __syncthreads();
    }
    float4 bi0 = *(const float4*)&bi[tn2*4];
    float4 bi1 = *(const float4*)&bi[tn2*4 + 128];
    float4 c0  = *(const float4*)&cn[b*C_ + tn2*4];
    float4 c1  = *(const float4*)&cn[b*C_ + tn2*4 + 128];
    #pragma unroll
    for (int i = 0; i < 16; i++) {
        size_t row = m0 + tm2*16 + i;
        float4 o0 = make_float4(acc[i][0]+bi0.x, acc[i][1]+bi0.y, acc[i][2]+bi0.z, acc[i][3]+bi0.w);
        float4 o1 = make_float4(acc[i][4]+bi1.x, acc[i][5]+bi1.y, acc[i][6]+bi1.z, acc[i][7]+bi1.w);
        *(float4*)&xp[row*C_ + tn2*4]       = o0;
        *(float4*)&xp[row*C_ + tn2*4 + 128] = o1;
        float dt = o0.x*c0.x + o0.y*c0.y + o0.z*c0.z + o0.w*c0.w
                 + o1.x*c1.x + o1.y*c1.y + o1.z*c1.z + o1.w*c1.w;
        float ss = o0.x*o0.x + o0.y*o0.y + o0.z*o0.z + o0.w*o0.w
                 + o1.x*o1.x + o1.y*o1.y + o1.z*o1.z + o1.w*o1.w;
        #pragma unroll
        for (int off = 16; off; off >>= 1) {
            dt += __shfl_xor(dt, off);
            ss += __shfl_xor(ss, off);
        }
        if (tn2 == 0) e[row] = dt / fmaxf(sqrtf(ss), 1e-12f);
    }
}

// ---------------- softmax over L per batch + bitonic sort (desc, idx-asc ties) ----------------
__global__ __launch_bounds__(1024) void softsort_kernel(
    const float* __restrict__ e, float* __restrict__ sim, int* __restrict__ idxo)
{
    __shared__ unsigned long long keys[L_];    // 64KB
    float* scratch = (float*)keys;
    const int b = blockIdx.x, tid = threadIdx.x;
    const int lane = tid & 63, wid = tid >> 6; // 16 waves
    const float* eb = e + (size_t)b*L_;
    float ev[8];
    #pragma unroll
    for (int s = 0; s < 8; s++) ev[s] = eb[tid + s*1024];
    float mx = ev[0];
    #pragma unroll
    for (int s = 1; s < 8; s++) mx = fmaxf(mx, ev[s]);
    #pragma unroll
    for (int off = 32; off; off >>= 1) mx = fmaxf(mx, __shfl_xor(mx, off));
    if (lane == 0) scratch[wid] = mx;
    __syncthreads();
    if (tid == 0) {
        float m2 = scratch[0];
        for (int i = 1; i < 16; i++) m2 = fmaxf(m2, scratch[i]);
        scratch[20] = m2;
    }
    __syncthreads();
    mx = scratch[20];
    float pv[8], sum = 0.f;
    #pragma unroll
    for (int s = 0; s < 8; s++) { pv[s] = expf(ev[s] - mx); sum += pv[s]; }
    #pragma unroll
    for (int off = 32; off; off >>= 1) sum += __shfl_xor(sum, off);
    __syncthreads();
    if (lane == 0) scratch[wid] = sum;
    __syncthreads();
    if (tid == 0) {
        float s2 = 0.f;
        for (int i = 0; i < 16; i++) s2 += scratch[i];
        scratch[21] = s2;
    }
    __syncthreads();
    float inv = 1.0f / scratch[21];
    __syncthreads();                           // everyone read scratch before keys overwrite
    #pragma unroll
    for (int s = 0; s < 8; s++) {
        int l = tid + s*1024;
        float sm = pv[s] * inv;
        sim[(size_t)b*L_ + l] = sm;
        keys[l] = ((unsigned long long)__float_as_uint(sm) << 32) | (unsigned)(0xFFFFFFFFu - l);
    }
    __syncthreads();
    for (int ksz = 2; ksz <= L_; ksz <<= 1) {
        for (int j = ksz >> 1; j > 0; j >>= 1) {
            #pragma unroll
            for (int s = 0; s < 8; s++) {
                int i = tid + s*1024;
                int ixj = i ^ j;
                if (ixj > i) {
                    unsigned long long a = keys[i], c = keys[ixj];
                    bool desc = ((i & ksz) == 0);
                    bool sw = desc ? (a < c) : (a > c);
                    if (sw) { keys[i] = c; keys[ixj] = a; }
                }
            }
            __syncthreads();
        }
    }
    for (int t = tid; t < KTOP; t += 1024)
        idxo[b*KTOP + t] = (int)(0xFFFFFFFFu - (unsigned)(keys[t] & 0xFFFFFFFFu));
}

// ---------------- y: tiled over 32 consecutive t with 51-row LDS window ----------------
#define TT 32
__global__ __launch_bounds__(256) void y_kernel(const float* __restrict__ xp,
    const int* __restrict__ idx, const float* __restrict__ conv_w,
    const float* __restrict__ cf, float* __restrict__ y)
{
    __shared__ float rows[(TT + JT - 1) * C_];   // 51 rows x 1KB = 51KB
    const int b = blockIdx.y;
    const int t0 = blockIdx.x * TT;
    const int tid = threadIdx.x;
    const int c4 = (tid & 63) * 4;
    const int tg = tid >> 6;
    const int* idxb = idx + b*KTOP;

    for (int s = tid; s < (TT + JT - 1) * 64; s += 256) {
        int r = s >> 6, cq = (s & 63) * 4;
        int gi = t0 - (JT - 1) + r;
        float4 v = make_float4(0.f, 0.f, 0.f, 0.f);
        if (gi >= 0 && gi < KTOP) {
            int l = idxb[gi];
            v = *(const float4*)&xp[((size_t)b*L_ + l)*C_ + cq];
        }
        *(float4*)&rows[r*C_ + cq] = v;
    }
    float4 cfr[JT];
    #pragma unroll
    for (int j = 0; j < JT; j++) cfr[j] = *(const float4*)&cf[j*C_ + c4];
    float4 cw = *(const float4*)&conv_w[c4];
    __syncthreads();

    #pragma unroll
    for (int u = 0; u < TT/4; u++) {
        int tl = tg + u*4;
        int t = t0 + tl;
        if (t < KTOP) {
            float4 acc = make_float4(0.f, 0.f, 0.f, 0.f);
            #pragma unroll
            for (int j = 0; j < JT; j++) {
                const float4 v = *(const float4*)&rows[(tl + JT - 1 - j)*C_ + c4];
                acc.x = fmaf(cfr[j].x, v.x, acc.x);
                acc.y = fmaf(cfr[j].y, v.y, acc.y);
                acc.z = fmaf(cfr[j].z, v.z, acc.z);
                acc.w = fmaf(cfr[j].w, v.w, acc.w);
            }
            acc.x *= cw.x; acc.y *= cw.y; acc.z *= cw.z; acc.w *= cw.w;
            *(float4*)&y[((size_t)b*KTOP + t)*C_ + c4] = acc;
        }
    }
}

// ---------------- residual copy ----------------
__global__ void copy_kernel(const float4* __restrict__ src, float4* __restrict__ dst)
{
    size_t n4 = (size_t)M1*C_/4;
    for (size_t i = (size_t)blockIdx.x*blockDim.x + threadIdx.x; i < n4;
         i += (size_t)gridDim.x*blockDim.x)
        dst[i] = src[i];
}

// ---------------- GEMM2 + scatter epilogue: out[b,l,:] = x[b,l,:] + y@WoT + bo ----------------
__global__ __launch_bounds__(256, 3) void gemm2_kernel(
    const float* __restrict__ y, const float* __restrict__ WoT,
    const float* __restrict__ bo, const float* __restrict__ x,
    const int* __restrict__ idx, float* __restrict__ out0)
{
    __shared__ float As[128*32];
    __shared__ float Bs[32*256];
    const int tid = threadIdx.x;
    const int tn2 = tid & 31;
    const int tm2 = tid >> 5;
    const int m0 = blockIdx.x * 128;

    float acc[16][8];
    #pragma unroll
    for (int i = 0; i < 16; i++)
        #pragma unroll
        for (int j = 0; j < 8; j++) acc[i][j] = 0.f;

    for (int k0 = 0; k0 < C_; k0 += 32) {
        #pragma unroll
        for (int it = 0; it < 4; it++) {
            int idx2 = tid + it*256;
            int ar = idx2 >> 3;
            int ak = (idx2 & 7) * 4;
            int m = m0 + ar;
            float4 v = (m < M2) ? *(const float4*)&y[(size_t)m*C_ + k0 + ak]
                                : make_float4(0.f, 0.f, 0.f, 0.f);
            *(float4*)&As[ar*32 + ak] = v;
        }
        #pragma unroll
        for (int it = 0; it < 8; it++) {
            int idx2 = tid + it*256;
            int br = idx2 >> 6;
            int bc = (idx2 & 63) * 4;
            *(float4*)&Bs[br*256 + bc] = *(const float4*)&WoT[(size_t)(k0 + br)*C_ + bc];
        }
        __syncthreads();
        #pragma unroll 4
        for (int kk = 0; kk < 32; kk++) {
            float4 b0 = *(const float4*)&Bs[kk*256 + tn2*4];
            float4 b1 = *(const float4*)&Bs[kk*256 + tn2*4 + 128];
            #pragma unroll
            for (int i = 0; i < 16; i++) {
                float a = As[(tm2*16 + i)*32 + kk];
                acc[i][0] = fmaf(a, b0.x, acc[i][0]);
                acc[i][1] = fmaf(a, b0.y, acc[i][1]);
                acc[i][2] = fmaf(a, b0.z, acc[i][2]);
                acc[i][3] = fmaf(a, b0.w, acc[i][3]);
                acc[i][4] = fmaf(a, b1.x, acc[i][4]);
                acc[i][5] = fmaf(a, b1.y, acc[i][5]);
                acc[i][6] = fmaf(a, b1.z, acc[i][6]);
                acc[i][7] = fmaf(a, b1.w, acc[i][7]);
            }
        }
        __syncthreads();
    }
    float4 bo0 = *(const float4*)&bo[tn2*4];
    float4 bo1 = *(const float4*)&bo[tn2*4 + 128];
    #pragma unroll
    for (int i = 0; i < 16; i++) {
        int m = m0 + tm2*16 + i;
        if (m < M2) {
            int b = m / KTOP, t = m - b*KTOP;
            int l = idx[b*KTOP + t];
            size_t base = ((size_t)b*L_ + l)*C_;
            float4 x0 = *(const float4*)&x[base + tn2*4];
            float4 x1 = *(const float4*)&x[base + tn2*4 + 128];
            float4 o0 = make_float4(acc[i][0]+bo0.x+x0.x, acc[i][1]+bo0.y+x0.y,
                                    acc[i][2]+bo0.z+x0.z, acc[i][3]+bo0.w+x0.w);
            float4 o1 = make_float4(acc[i][4]+bo1.x+x1.x, acc[i][5]+bo1.y+x1.y,
                                    acc[i][6]+bo1.z+x1.z, acc[i][7]+bo1.w+x1.w);
            *(float4*)&out0[base + tn2*4]       = o0;
            *(float4*)&out0[base + tn2*4 + 128] = o1;
        }
    }
}

extern "C" void kernel_launch(void* const* d_in, const int* in_sizes, int n_in,
                              void* d_out, int out_size, void* d_ws, size_t ws_size,
                              hipStream_t stream)
{
    const float* x      = (const float*)d_in[0];
    const float* alpha  = (const float*)d_in[1];
    const float* dyt_w  = (const float*)d_in[2];
    const float* dyt_b  = (const float*)d_in[3];
    const float* Wi     = (const float*)d_in[4];
    const float* bi     = (const float*)d_in[5];
    const float* conv_w = (const float*)d_in[6];
    const float* A      = (const float*)d_in[7];
    const float* Bp     = (const float*)d_in[8];
    const float* Cp     = (const float*)d_in[9];
    const float* Wo     = (const float*)d_in[10];
    const float* bo     = (const float*)d_in[11];

    float* ws  = (float*)d_ws;
    float* xp  = ws + XP_OFF;
    float* yb  = ws + Y_OFF;
    float* e   = ws + E_OFF;
    float* cn  = ws + CN_OFF;
    float* cf  = ws + CF_OFF;
    int*   idx = (int*)(ws + IDX_OFF);
    float* WiT = ws + WIT_OFF;
    float* WoT = ws + WOT_OFF;

    float* out0 = (float*)d_out;
    float* sim  = out0 + (size_t)M1*C_;

    transpose_kernel<<<dim3(8,8,2), dim3(32,8), 0, stream>>>(Wi, Wo, WiT, WoT);
    coef_kernel<<<1, 256, 0, stream>>>(A, Bp, Cp, cf);
    center2_kernel<<<B_, 256, 0, stream>>>(x, WiT, bi, alpha, dyt_w, dyt_b, cn);
    gemm1_kernel<<<M1/128, 256, 0, stream>>>(x, WiT, bi, alpha, dyt_w, dyt_b, cn, xp, e);
    softsort_kernel<<<B_, 1024, 0, stream>>>(e, sim, idx);
    y_kernel<<<dim3((KTOP + TT - 1)/TT, B_), 256, 0, stream>>>(xp, idx, conv_w, cf, yb);
    copy_kernel<<<2048, 256, 0, stream>>>((const float4*)x, (float4*)out0);
    gemm2_kernel<<<(M2 + 127)/128, 256, 0, stream>>>(yb, WoT, bo, x, idx, out0);
}

// Round 4
// 725.446 us; speedup vs baseline: 5.3016x; 5.3016x over previous
//
#include <hip/hip_runtime.h>
#include <math.h>

#define B_ 16
#define L_ 8192
#define C_ 256
#define KTOP 2457            // max(1, int(8192*0.3))
#define JT 20                // recurrence taps; ||A||^20 ~ 1e-16 -> exact at fp32
#define M1 (B_*L_)           // 131072
#define M2 (B_*KTOP)         // 39312

// workspace layout in floats
#define XP_OFF  ((size_t)0)
#define Y_OFF   (XP_OFF + (size_t)M1*C_)        // 33554432
#define E_OFF   (Y_OFF  + (size_t)M2*C_)        // 43618304
#define CN_OFF  (E_OFF  + (size_t)M1)           // 43749376
#define CF_OFF  (CN_OFF + (size_t)B_*C_)        // 43753472
#define IDX_OFF (CF_OFF + (size_t)JT*C_)        // 43758592 (ints)
#define WIT_OFF (IDX_OFF + (size_t)M2)          // 43797904
#define WOT_OFF (WIT_OFF + (size_t)C_*C_)       // 43863440

// ---------------- transpose Wi/Wo (256x256 each) into [K][N] layout ----------------
__global__ void transpose_kernel(const float* __restrict__ Wi, const float* __restrict__ Wo,
                                 float* __restrict__ WiT, float* __restrict__ WoT)
{
    __shared__ float t[32][33];
    const float* src = blockIdx.z ? Wo : Wi;
    float* dst = blockIdx.z ? WoT : WiT;
    int r0 = blockIdx.y * 32, c0 = blockIdx.x * 32;
    int tx = threadIdx.x, ty = threadIdx.y;      // 32 x 8
    #pragma unroll
    for (int r = 0; r < 4; r++)
        t[ty + r*8][tx] = src[(size_t)(r0 + ty + r*8)*C_ + c0 + tx];
    __syncthreads();
    #pragma unroll
    for (int r = 0; r < 4; r++)
        dst[(size_t)(c0 + ty + r*8)*C_ + r0 + tx] = t[tx][ty + r*8];
}

// ---------------- coef: cf[j][c] = sigmoid(Cp[c,:]) . (A^j sigmoid(Bp)) ----------------
__global__ void coef_kernel(const float* __restrict__ A, const float* __restrict__ Bp,
                            const float* __restrict__ Cp, float* __restrict__ cf)
{
    int c = threadIdx.x;                       // 256 threads
    __shared__ float As[256];
    __shared__ float v0[16];
    As[c] = A[c];
    if (c < 16) v0[c] = 1.0f / (1.0f + expf(-Bp[c]));
    float sC[16];
    #pragma unroll
    for (int i = 0; i < 16; i++) sC[i] = 1.0f / (1.0f + expf(-Cp[c*16 + i]));
    __syncthreads();
    float v[16];
    #pragma unroll
    for (int i = 0; i < 16; i++) v[i] = v0[i];
    for (int j = 0; j < JT; j++) {
        float d = 0.f;
        #pragma unroll
        for (int i = 0; i < 16; i++) d += sC[i] * v[i];
        cf[j*C_ + c] = d;
        float nv[16];
        #pragma unroll
        for (int i = 0; i < 16; i++) {
            float s = 0.f;
            #pragma unroll
            for (int m = 0; m < 16; m++) s += As[i*16 + m] * v[m];
            nv[i] = s;
        }
        #pragma unroll
        for (int i = 0; i < 16; i++) v[i] = nv[i];
    }
}

// ---------------- center2: cn[b,:] = normalize(dyt(x[b,L/2,:]) @ WiT + bi) ----------------
__global__ void center2_kernel(const float* __restrict__ x, const float* __restrict__ WiT,
                               const float* __restrict__ bi, const float* __restrict__ alpha,
                               const float* __restrict__ dw, const float* __restrict__ db,
                               float* __restrict__ cn)
{
    __shared__ float xn[256];
    __shared__ float red[4];
    int b = blockIdx.x, c = threadIdx.x;       // 256 threads
    float al = alpha[0];
    size_t base = ((size_t)b*L_ + L_/2)*C_;
    xn[c] = tanhf(al*x[base + c])*dw[c] + db[c];
    __syncthreads();
    float s = bi[c];
    #pragma unroll 8
    for (int k = 0; k < 256; k++) s = fmaf(xn[k], WiT[(size_t)k*C_ + c], s);
    float ss = s*s;
    #pragma unroll
    for (int off = 32; off; off >>= 1) ss += __shfl_xor(ss, off);
    if ((c & 63) == 0) red[c >> 6] = ss;
    __syncthreads();
    float tot = red[0] + red[1] + red[2] + red[3];
    float inv = 1.0f / fmaxf(sqrtf(tot), 1e-12f);
    cn[b*C_ + c] = s * inv;
}

// ---------------- GEMM1 + fused e: xp = dyt(x)@WiT + bi ; e[m] = xp.cn/||xp|| ----------------
// BM=128, BN=256(full), BK=32, 256 threads, 16x8 micro-tile
// As[128][32] row-major: staging writes contiguous (conflict-free); reads scalar 2-addr broadcast
// __launch_bounds__(256,2): VGPR budget 256 — (256,3) caps at 168 and SPILLS acc (round-3 9.6GB scratch)
__global__ __launch_bounds__(256, 2) void gemm1_kernel(
    const float* __restrict__ x, const float* __restrict__ WiT,
    const float* __restrict__ bi, const float* __restrict__ alpha,
    const float* __restrict__ dw, const float* __restrict__ db,
    const float* __restrict__ cn, float* __restrict__ xp, float* __restrict__ e)
{
    __shared__ float As[128*32];   // [m][kk] row-major
    __shared__ float Bs[32*256];   // [kk][n]
    const int tid = threadIdx.x;
    const int tn2 = tid & 31;      // cols tn2*4..+3 and 128+tn2*4..+3
    const int tm2 = tid >> 5;      // rows tm2*16..+15
    const int m0 = blockIdx.x * 128;
    const int b  = m0 >> 13;
    const float al = alpha[0];

    float acc[16][8];
    #pragma unroll
    for (int i = 0; i < 16; i++)
        #pragma unroll
        for (int j = 0; j < 8; j++) acc[i][j] = 0.f;

    for (int k0 = 0; k0 < C_; k0 += 32) {
        // A stage: 128x32 tile, dyt transform, row-major, contiguous writes
        #pragma unroll
        for (int it = 0; it < 4; it++) {
            int idx = tid + it*256;
            int ar = idx >> 3;             // row 0..127
            int ak = (idx & 7) * 4;        // k 0,4,..,28
            float4 v  = *(const float4*)&x[(size_t)(m0 + ar)*C_ + k0 + ak];
            float4 w4 = *(const float4*)&dw[k0 + ak];
            float4 b4 = *(const float4*)&db[k0 + ak];
            float4 o;
            o.x = tanhf(al*v.x)*w4.x + b4.x;
            o.y = tanhf(al*v.y)*w4.y + b4.y;
            o.z = tanhf(al*v.z)*w4.z + b4.z;
            o.w = tanhf(al*v.w)*w4.w + b4.w;
            *(float4*)&As[ar*32 + ak] = o;
        }
        // B stage: row copy (contiguous, conflict-free)
        #pragma unroll
        for (int it = 0; it < 8; it++) {
            int idx = tid + it*256;
            int br = idx >> 6;
            int bc = (idx & 63) * 4;
            *(float4*)&Bs[br*256 + bc] = *(const float4*)&WiT[(size_t)(k0 + br)*C_ + bc];
        }
        __syncthreads();
        #pragma unroll 2
        for (int kk = 0; kk < 32; kk++) {
            float4 b0 = *(const float4*)&Bs[kk*256 + tn2*4];
            float4 b1 = *(const float4*)&Bs[kk*256 + tn2*4 + 128];
            #pragma unroll
            for (int i = 0; i < 16; i++) {
                float a = As[(tm2*16 + i)*32 + kk];
                acc[i][0] = fmaf(a, b0.x, acc[i][0]);
                acc[i][1] = fmaf(a, b0.y, acc[i][1]);
                acc[i][2] = fmaf(a, b0.z, acc[i][2]);
                acc[i][3] = fmaf(a, b0.w, acc[i][3]);
                acc[i][4] = fmaf(a, b1.x, acc[i][4]);
                acc[i][5] = fmaf(a, b1.y, acc[i][5]);
                acc[i][6] = fmaf(a, b1.z, acc[i][6]);
                acc[i][7] = fmaf(a, b1.w, acc[i][7]);
            }
        }
        __syncthreads();
    }
    float4 bi0 = *(const float4*)&bi[tn2*4];
    float4 bi1 = *(const float4*)&bi[tn2*4 + 128];
    float4 c0  = *(const float4*)&cn[b*C_ + tn2*4];
    float4 c1  = *(const float4*)&cn[b*C_ + tn2*4 + 128];
    #pragma unroll
    for (int i = 0; i < 16; i++) {
        size_t row = m0 + tm2*16 + i;
        float4 o0 = make_float4(acc[i][0]+bi0.x, acc[i][1]+bi0.y, acc[i][2]+bi0.z, acc[i][3]+bi0.w);
        float4 o1 = make_float4(acc[i][4]+bi1.x, acc[i][5]+bi1.y, acc[i][6]+bi1.z, acc[i][7]+bi1.w);
        *(float4*)&xp[row*C_ + tn2*4]       = o0;
        *(float4*)&xp[row*C_ + tn2*4 + 128] = o1;
        float dt = o0.x*c0.x + o0.y*c0.y + o0.z*c0.z + o0.w*c0.w
                 + o1.x*c1.x + o1.y*c1.y + o1.z*c1.z + o1.w*c1.w;
        float ss = o0.x*o0.x + o0.y*o0.y + o0.z*o0.z + o0.w*o0.w
                 + o1.x*o1.x + o1.y*o1.y + o1.z*o1.z + o1.w*o1.w;
        #pragma unroll
        for (int off = 16; off; off >>= 1) {
            dt += __shfl_xor(dt, off);
            ss += __shfl_xor(ss, off);
        }
        if (tn2 == 0) e[row] = dt / fmaxf(sqrtf(ss), 1e-12f);
    }
}

// ---------------- softmax over L per batch + bitonic sort (desc, idx-asc ties) ----------------
__global__ __launch_bounds__(1024) void softsort_kernel(
    const float* __restrict__ e, float* __restrict__ sim, int* __restrict__ idxo)
{
    __shared__ unsigned long long keys[L_];    // 64KB
    float* scratch = (float*)keys;
    const int b = blockIdx.x, tid = threadIdx.x;
    const int lane = tid & 63, wid = tid >> 6; // 16 waves
    const float* eb = e + (size_t)b*L_;
    float ev[8];
    #pragma unroll
    for (int s = 0; s < 8; s++) ev[s] = eb[tid + s*1024];
    float mx = ev[0];
    #pragma unroll
    for (int s = 1; s < 8; s++) mx = fmaxf(mx, ev[s]);
    #pragma unroll
    for (int off = 32; off; off >>= 1) mx = fmaxf(mx, __shfl_xor(mx, off));
    if (lane == 0) scratch[wid] = mx;
    __syncthreads();
    if (tid == 0) {
        float m2 = scratch[0];
        for (int i = 1; i < 16; i++) m2 = fmaxf(m2, scratch[i]);
        scratch[20] = m2;
    }
    __syncthreads();
    mx = scratch[20];
    float pv[8], sum = 0.f;
    #pragma unroll
    for (int s = 0; s < 8; s++) { pv[s] = expf(ev[s] - mx); sum += pv[s]; }
    #pragma unroll
    for (int off = 32; off; off >>= 1) sum += __shfl_xor(sum, off);
    __syncthreads();
    if (lane == 0) scratch[wid] = sum;
    __syncthreads();
    if (tid == 0) {
        float s2 = 0.f;
        for (int i = 0; i < 16; i++) s2 += scratch[i];
        scratch[21] = s2;
    }
    __syncthreads();
    float inv = 1.0f / scratch[21];
    __syncthreads();                           // everyone read scratch before keys overwrite
    #pragma unroll
    for (int s = 0; s < 8; s++) {
        int l = tid + s*1024;
        float sm = pv[s] * inv;
        sim[(size_t)b*L_ + l] = sm;
        keys[l] = ((unsigned long long)__float_as_uint(sm) << 32) | (unsigned)(0xFFFFFFFFu - l);
    }
    __syncthreads();
    for (int ksz = 2; ksz <= L_; ksz <<= 1) {
        for (int j = ksz >> 1; j > 0; j >>= 1) {
            #pragma unroll
            for (int s = 0; s < 8; s++) {
                int i = tid + s*1024;
                int ixj = i ^ j;
                if (ixj > i) {
                    unsigned long long a = keys[i], c = keys[ixj];
                    bool desc = ((i & ksz) == 0);
                    bool sw = desc ? (a < c) : (a > c);
                    if (sw) { keys[i] = c; keys[ixj] = a; }
                }
            }
            __syncthreads();
        }
    }
    for (int t = tid; t < KTOP; t += 1024)
        idxo[b*KTOP + t] = (int)(0xFFFFFFFFu - (unsigned)(keys[t] & 0xFFFFFFFFu));
}

// ---------------- y: tiled over 32 consecutive t with 51-row LDS window ----------------
#define TT 32
__global__ __launch_bounds__(256) void y_kernel(const float* __restrict__ xp,
    const int* __restrict__ idx, const float* __restrict__ conv_w,
    const float* __restrict__ cf, float* __restrict__ y)
{
    __shared__ float rows[(TT + JT - 1) * C_];   // 51 rows x 1KB = 51KB
    const int b = blockIdx.y;
    const int t0 = blockIdx.x * TT;
    const int tid = threadIdx.x;
    const int c4 = (tid & 63) * 4;
    const int tg = tid >> 6;
    const int* idxb = idx + b*KTOP;

    for (int s = tid; s < (TT + JT - 1) * 64; s += 256) {
        int r = s >> 6, cq = (s & 63) * 4;
        int gi = t0 - (JT - 1) + r;
        float4 v = make_float4(0.f, 0.f, 0.f, 0.f);
        if (gi >= 0 && gi < KTOP) {
            int l = idxb[gi];
            v = *(const float4*)&xp[((size_t)b*L_ + l)*C_ + cq];
        }
        *(float4*)&rows[r*C_ + cq] = v;
    }
    float4 cfr[JT];
    #pragma unroll
    for (int j = 0; j < JT; j++) cfr[j] = *(const float4*)&cf[j*C_ + c4];
    float4 cw = *(const float4*)&conv_w[c4];
    __syncthreads();

    #pragma unroll
    for (int u = 0; u < TT/4; u++) {
        int tl = tg + u*4;
        int t = t0 + tl;
        if (t < KTOP) {
            float4 acc = make_float4(0.f, 0.f, 0.f, 0.f);
            #pragma unroll
            for (int j = 0; j < JT; j++) {
                const float4 v = *(const float4*)&rows[(tl + JT - 1 - j)*C_ + c4];
                acc.x = fmaf(cfr[j].x, v.x, acc.x);
                acc.y = fmaf(cfr[j].y, v.y, acc.y);
                acc.z = fmaf(cfr[j].z, v.z, acc.z);
                acc.w = fmaf(cfr[j].w, v.w, acc.w);
            }
            acc.x *= cw.x; acc.y *= cw.y; acc.z *= cw.z; acc.w *= cw.w;
            *(float4*)&y[((size_t)b*KTOP + t)*C_ + c4] = acc;
        }
    }
}

// ---------------- residual copy ----------------
__global__ void copy_kernel(const float4* __restrict__ src, float4* __restrict__ dst)
{
    size_t n4 = (size_t)M1*C_/4;
    for (size_t i = (size_t)blockIdx.x*blockDim.x + threadIdx.x; i < n4;
         i += (size_t)gridDim.x*blockDim.x)
        dst[i] = src[i];
}

// ---------------- GEMM2 + scatter epilogue: out[b,l,:] = x[b,l,:] + y@WoT + bo ----------------
__global__ __launch_bounds__(256, 2) void gemm2_kernel(
    const float* __restrict__ y, const float* __restrict__ WoT,
    const float* __restrict__ bo, const float* __restrict__ x,
    const int* __restrict__ idx, float* __restrict__ out0)
{
    __shared__ float As[128*32];
    __shared__ float Bs[32*256];
    const int tid = threadIdx.x;
    const int tn2 = tid & 31;
    const int tm2 = tid >> 5;
    const int m0 = blockIdx.x * 128;

    float acc[16][8];
    #pragma unroll
    for (int i = 0; i < 16; i++)
        #pragma unroll
        for (int j = 0; j < 8; j++) acc[i][j] = 0.f;

    for (int k0 = 0; k0 < C_; k0 += 32) {
        #pragma unroll
        for (int it = 0; it < 4; it++) {
            int idx2 = tid + it*256;
            int ar = idx2 >> 3;
            int ak = (idx2 & 7) * 4;
            int m = m0 + ar;
            float4 v = (m < M2) ? *(const float4*)&y[(size_t)m*C_ + k0 + ak]
                                : make_float4(0.f, 0.f, 0.f, 0.f);
            *(float4*)&As[ar*32 + ak] = v;
        }
        #pragma unroll
        for (int it = 0; it < 8; it++) {
            int idx2 = tid + it*256;
            int br = idx2 >> 6;
            int bc = (idx2 & 63) * 4;
            *(float4*)&Bs[br*256 + bc] = *(const float4*)&WoT[(size_t)(k0 + br)*C_ + bc];
        }
        __syncthreads();
        #pragma unroll 2
        for (int kk = 0; kk < 32; kk++) {
            float4 b0 = *(const float4*)&Bs[kk*256 + tn2*4];
            float4 b1 = *(const float4*)&Bs[kk*256 + tn2*4 + 128];
            #pragma unroll
            for (int i = 0; i < 16; i++) {
                float a = As[(tm2*16 + i)*32 + kk];
                acc[i][0] = fmaf(a, b0.x, acc[i][0]);
                acc[i][1] = fmaf(a, b0.y, acc[i][1]);
                acc[i][2] = fmaf(a, b0.z, acc[i][2]);
                acc[i][3] = fmaf(a, b0.w, acc[i][3]);
                acc[i][4] = fmaf(a, b1.x, acc[i][4]);
                acc[i][5] = fmaf(a, b1.y, acc[i][5]);
                acc[i][6] = fmaf(a, b1.z, acc[i][6]);
                acc[i][7] = fmaf(a, b1.w, acc[i][7]);
            }
        }
        __syncthreads();
    }
    float4 bo0 = *(const float4*)&bo[tn2*4];
    float4 bo1 = *(const float4*)&bo[tn2*4 + 128];
    #pragma unroll
    for (int i = 0; i < 16; i++) {
        int m = m0 + tm2*16 + i;
        if (m < M2) {
            int b = m / KTOP, t = m - b*KTOP;
            int l = idx[b*KTOP + t];
            size_t base = ((size_t)b*L_ + l)*C_;
            float4 x0 = *(const float4*)&x[base + tn2*4];
            float4 x1 = *(const float4*)&x[base + tn2*4 + 128];
            float4 o0 = make_float4(acc[i][0]+bo0.x+x0.x, acc[i][1]+bo0.y+x0.y,
                                    acc[i][2]+bo0.z+x0.z, acc[i][3]+bo0.w+x0.w);
            float4 o1 = make_float4(acc[i][4]+bo1.x+x1.x, acc[i][5]+bo1.y+x1.y,
                                    acc[i][6]+bo1.z+x1.z, acc[i][7]+bo1.w+x1.w);
            *(float4*)&out0[base + tn2*4]       = o0;
            *(float4*)&out0[base + tn2*4 + 128] = o1;
        }
    }
}

extern "C" void kernel_launch(void* const* d_in, const int* in_sizes, int n_in,
                              void* d_out, int out_size, void* d_ws, size_t ws_size,
                              hipStream_t stream)
{
    const float* x      = (const float*)d_in[0];
    const float* alpha  = (const float*)d_in[1];
    const float* dyt_w  = (const float*)d_in[2];
    const float* dyt_b  = (const float*)d_in[3];
    const float* Wi     = (const float*)d_in[4];
    const float* bi     = (const float*)d_in[5];
    const float* conv_w = (const float*)d_in[6];
    const float* A      = (const float*)d_in[7];
    const float* Bp     = (const float*)d_in[8];
    const float* Cp     = (const float*)d_in[9];
    const float* Wo     = (const float*)d_in[10];
    const float* bo     = (const float*)d_in[11];

    float* ws  = (float*)d_ws;
    float* xp  = ws + XP_OFF;
    float* yb  = ws + Y_OFF;
    float* e   = ws + E_OFF;
    float* cn  = ws + CN_OFF;
    float* cf  = ws + CF_OFF;
    int*   idx = (int*)(ws + IDX_OFF);
    float* WiT = ws + WIT_OFF;
    float* WoT = ws + WOT_OFF;

    float* out0 = (float*)d_out;
    float* sim  = out0 + (size_t)M1*C_;

    transpose_kernel<<<dim3(8,8,2), dim3(32,8), 0, stream>>>(Wi, Wo, WiT, WoT);
    coef_kernel<<<1, 256, 0, stream>>>(A, Bp, Cp, cf);
    center2_kernel<<<B_, 256, 0, stream>>>(x, WiT, bi, alpha, dyt_w, dyt_b, cn);
    gemm1_kernel<<<M1/128, 256, 0, stream>>>(x, WiT, bi, alpha, dyt_w, dyt_b, cn, xp, e);
    softsort_kernel<<<B_, 1024, 0, stream>>>(e, sim, idx);
    y_kernel<<<dim3((KTOP + TT - 1)/TT, B_), 256, 0, stream>>>(xp, idx, conv_w, cf, yb);
    copy_kernel<<<2048, 256, 0, stream>>>((const float4*)x, (float4*)out0);
    gemm2_kernel<<<(M2 + 127)/128, 256, 0, stream>>>(yb, WoT, bo, x, idx, out0);
}

// Round 5
// 697.721 us; speedup vs baseline: 5.5123x; 1.0397x over previous
//
#include <hip/hip_runtime.h>
#include <math.h>

#define B_ 16
#define L_ 8192
#define C_ 256
#define KTOP 2457            // max(1, int(8192*0.3))
#define JT 20                // recurrence taps; ||A||^20 ~ 1e-16 -> exact at fp32
#define M1 (B_*L_)           // 131072
#define M2 (B_*KTOP)         // 39312

// workspace layout in floats
#define XP_OFF  ((size_t)0)
#define Y_OFF   (XP_OFF + (size_t)M1*C_)        // 33554432
#define E_OFF   (Y_OFF  + (size_t)M2*C_)        // 43618304
#define CN_OFF  (E_OFF  + (size_t)M1)           // 43749376
#define CF_OFF  (CN_OFF + (size_t)B_*C_)        // 43753472
#define IDX_OFF (CF_OFF + (size_t)JT*C_)        // 43758592 (ints)
#define WIT_OFF (IDX_OFF + (size_t)M2)          // 43797904
#define WOT_OFF (WIT_OFF + (size_t)C_*C_)       // 43863440
// u64 key buffers alias the (not-yet-written) yb region: keys die before y_kernel writes yb

// ---------------- transpose Wi/Wo (256x256 each) into [K][N] layout ----------------
__global__ void transpose_kernel(const float* __restrict__ Wi, const float* __restrict__ Wo,
                                 float* __restrict__ WiT, float* __restrict__ WoT)
{
    __shared__ float t[32][33];
    const float* src = blockIdx.z ? Wo : Wi;
    float* dst = blockIdx.z ? WoT : WiT;
    int r0 = blockIdx.y * 32, c0 = blockIdx.x * 32;
    int tx = threadIdx.x, ty = threadIdx.y;      // 32 x 8
    #pragma unroll
    for (int r = 0; r < 4; r++)
        t[ty + r*8][tx] = src[(size_t)(r0 + ty + r*8)*C_ + c0 + tx];
    __syncthreads();
    #pragma unroll
    for (int r = 0; r < 4; r++)
        dst[(size_t)(c0 + ty + r*8)*C_ + r0 + tx] = t[tx][ty + r*8];
}

// ---------------- coef: cf[j][c] = sigmoid(Cp[c,:]) . (A^j sigmoid(Bp)) ----------------
__global__ void coef_kernel(const float* __restrict__ A, const float* __restrict__ Bp,
                            const float* __restrict__ Cp, float* __restrict__ cf)
{
    int c = threadIdx.x;                       // 256 threads
    __shared__ float As[256];
    __shared__ float v0[16];
    As[c] = A[c];
    if (c < 16) v0[c] = 1.0f / (1.0f + expf(-Bp[c]));
    float sC[16];
    #pragma unroll
    for (int i = 0; i < 16; i++) sC[i] = 1.0f / (1.0f + expf(-Cp[c*16 + i]));
    __syncthreads();
    float v[16];
    #pragma unroll
    for (int i = 0; i < 16; i++) v[i] = v0[i];
    for (int j = 0; j < JT; j++) {
        float d = 0.f;
        #pragma unroll
        for (int i = 0; i < 16; i++) d += sC[i] * v[i];
        cf[j*C_ + c] = d;
        float nv[16];
        #pragma unroll
        for (int i = 0; i < 16; i++) {
            float s = 0.f;
            #pragma unroll
            for (int m = 0; m < 16; m++) s += As[i*16 + m] * v[m];
            nv[i] = s;
        }
        #pragma unroll
        for (int i = 0; i < 16; i++) v[i] = nv[i];
    }
}

// ---------------- center2: cn[b,:] = normalize(dyt(x[b,L/2,:]) @ WiT + bi) ----------------
__global__ void center2_kernel(const float* __restrict__ x, const float* __restrict__ WiT,
                               const float* __restrict__ bi, const float* __restrict__ alpha,
                               const float* __restrict__ dw, const float* __restrict__ db,
                               float* __restrict__ cn)
{
    __shared__ float xn[256];
    __shared__ float red[4];
    int b = blockIdx.x, c = threadIdx.x;       // 256 threads
    float al = alpha[0];
    size_t base = ((size_t)b*L_ + L_/2)*C_;
    xn[c] = tanhf(al*x[base + c])*dw[c] + db[c];
    __syncthreads();
    float s = bi[c];
    #pragma unroll 8
    for (int k = 0; k < 256; k++) s = fmaf(xn[k], WiT[(size_t)k*C_ + c], s);
    float ss = s*s;
    #pragma unroll
    for (int off = 32; off; off >>= 1) ss += __shfl_xor(ss, off);
    if ((c & 63) == 0) red[c >> 6] = ss;
    __syncthreads();
    float tot = red[0] + red[1] + red[2] + red[3];
    float inv = 1.0f / fmaxf(sqrtf(tot), 1e-12f);
    cn[b*C_ + c] = s * inv;
}

// ---------------- GEMM1 + fused e + fused residual copy ----------------
// xp = dyt(x)@WiT + bi ; e[m] = xp.cn/||xp|| ; out0[m,:] = x[m,:]
// BM=128, BN=256(full), BK=32, 256 threads, 16x8 micro-tile, T14 reg prefetch.
// __launch_bounds__(256,2): VGPR budget 256 — (256,3) caps at 168 and SPILLS acc (round-3 9.6GB scratch)
__global__ __launch_bounds__(256, 2) void gemm1_kernel(
    const float* __restrict__ x, const float* __restrict__ WiT,
    const float* __restrict__ bi, const float* __restrict__ alpha,
    const float* __restrict__ dw, const float* __restrict__ db,
    const float* __restrict__ cn, float* __restrict__ xp, float* __restrict__ e,
    float* __restrict__ out0)
{
    __shared__ float As[128*32];   // [m][kk] row-major: contiguous stage writes, broadcast reads
    __shared__ float Bs[32*256];   // [kk][n]
    const int tid = threadIdx.x;
    const int tn2 = tid & 31;      // cols tn2*4..+3 and 128+tn2*4..+3
    const int tm2 = tid >> 5;      // rows tm2*16..+15
    const int m0 = blockIdx.x * 128;
    const int b  = m0 >> 13;
    const float al = alpha[0];
    const int ar = tid >> 3;             // A stage row 0..127 (it-invariant part uses +0)
    const int ak = (tid & 7) * 4;        // A stage k 0,4,..,28
    const int br = tid >> 6;             // B stage row
    const int bc = (tid & 63) * 4;

    float acc[16][8];
    #pragma unroll
    for (int i = 0; i < 16; i++)
        #pragma unroll
        for (int j = 0; j < 8; j++) acc[i][j] = 0.f;

    // prologue prefetch k0=0
    float4 xa[4], wb[8];
    #pragma unroll
    for (int it = 0; it < 4; it++)
        xa[it] = *(const float4*)&x[(size_t)(m0 + ar + it*32)*C_ + ak];
    #pragma unroll
    for (int it = 0; it < 8; it++)
        wb[it] = *(const float4*)&WiT[(size_t)(br + it*4)*C_ + bc];

    for (int k0 = 0; k0 < C_; k0 += 32) {
        // stage from regs (dyt transform on A)
        float4 w4 = *(const float4*)&dw[k0 + ak];
        float4 b4 = *(const float4*)&db[k0 + ak];
        #pragma unroll
        for (int it = 0; it < 4; it++) {
            float4 v = xa[it];
            float4 o;
            o.x = tanhf(al*v.x)*w4.x + b4.x;
            o.y = tanhf(al*v.y)*w4.y + b4.y;
            o.z = tanhf(al*v.z)*w4.z + b4.z;
            o.w = tanhf(al*v.w)*w4.w + b4.w;
            *(float4*)&As[(ar + it*32)*32 + ak] = o;
        }
        #pragma unroll
        for (int it = 0; it < 8; it++)
            *(float4*)&Bs[(br + it*4)*256 + bc] = wb[it];
        __syncthreads();
        // prefetch next tile (hides HBM/L2 latency under compute)
        if (k0 + 32 < C_) {
            #pragma unroll
            for (int it = 0; it < 4; it++)
                xa[it] = *(const float4*)&x[(size_t)(m0 + ar + it*32)*C_ + k0 + 32 + ak];
            #pragma unroll
            for (int it = 0; it < 8; it++)
                wb[it] = *(const float4*)&WiT[(size_t)(k0 + 32 + br + it*4)*C_ + bc];
        }
        #pragma unroll 2
        for (int kk = 0; kk < 32; kk++) {
            float4 b0 = *(const float4*)&Bs[kk*256 + tn2*4];
            float4 b1 = *(const float4*)&Bs[kk*256 + tn2*4 + 128];
            #pragma unroll
            for (int i = 0; i < 16; i++) {
                float a = As[(tm2*16 + i)*32 + kk];
                acc[i][0] = fmaf(a, b0.x, acc[i][0]);
                acc[i][1] = fmaf(a, b0.y, acc[i][1]);
                acc[i][2] = fmaf(a, b0.z, acc[i][2]);
                acc[i][3] = fmaf(a, b0.w, acc[i][3]);
                acc[i][4] = fmaf(a, b1.x, acc[i][4]);
                acc[i][5] = fmaf(a, b1.y, acc[i][5]);
                acc[i][6] = fmaf(a, b1.z, acc[i][6]);
                acc[i][7] = fmaf(a, b1.w, acc[i][7]);
            }
        }
        __syncthreads();
    }
    float4 bi0 = *(const float4*)&bi[tn2*4];
    float4 bi1 = *(const float4*)&bi[tn2*4 + 128];
    float4 c0  = *(const float4*)&cn[b*C_ + tn2*4];
    float4 c1  = *(const float4*)&cn[b*C_ + tn2*4 + 128];
    #pragma unroll
    for (int i = 0; i < 16; i++) {
        size_t row = m0 + tm2*16 + i;
        float4 o0 = make_float4(acc[i][0]+bi0.x, acc[i][1]+bi0.y, acc[i][2]+bi0.z, acc[i][3]+bi0.w);
        float4 o1 = make_float4(acc[i][4]+bi1.x, acc[i][5]+bi1.y, acc[i][6]+bi1.z, acc[i][7]+bi1.w);
        *(float4*)&xp[row*C_ + tn2*4]       = o0;
        *(float4*)&xp[row*C_ + tn2*4 + 128] = o1;
        // fused residual: out0 = x (topk rows overwritten later by gemm2)
        *(float4*)&out0[row*C_ + tn2*4]       = *(const float4*)&x[row*C_ + tn2*4];
        *(float4*)&out0[row*C_ + tn2*4 + 128] = *(const float4*)&x[row*C_ + tn2*4 + 128];
        float dt = o0.x*c0.x + o0.y*c0.y + o0.z*c0.z + o0.w*c0.w
                 + o1.x*c1.x + o1.y*c1.y + o1.z*c1.z + o1.w*c1.w;
        float ss = o0.x*o0.x + o0.y*o0.y + o0.z*o0.z + o0.w*o0.w
                 + o1.x*o1.x + o1.y*o1.y + o1.z*o1.z + o1.w*o1.w;
        #pragma unroll
        for (int off = 16; off; off >>= 1) {
            dt += __shfl_xor(dt, off);
            ss += __shfl_xor(ss, off);
        }
        if (tn2 == 0) e[row] = dt / fmaxf(sqrtf(ss), 1e-12f);
    }
}

// ---------------- softmax per batch; emit sim + u64 keys (sim desc, idx asc) ----------------
__global__ __launch_bounds__(1024) void softmax_kernel(
    const float* __restrict__ e, float* __restrict__ sim, unsigned long long* __restrict__ kw)
{
    __shared__ float scratch[32];
    const int b = blockIdx.x, tid = threadIdx.x;
    const int lane = tid & 63, wid = tid >> 6; // 16 waves
    const float* eb = e + (size_t)b*L_;
    float ev[8];
    #pragma unroll
    for (int s = 0; s < 8; s++) ev[s] = eb[tid + s*1024];
    float mx = ev[0];
    #pragma unroll
    for (int s = 1; s < 8; s++) mx = fmaxf(mx, ev[s]);
    #pragma unroll
    for (int off = 32; off; off >>= 1) mx = fmaxf(mx, __shfl_xor(mx, off));
    if (lane == 0) scratch[wid] = mx;
    __syncthreads();
    if (tid == 0) {
        float m2 = scratch[0];
        for (int i = 1; i < 16; i++) m2 = fmaxf(m2, scratch[i]);
        scratch[20] = m2;
    }
    __syncthreads();
    mx = scratch[20];
    float pv[8], sum = 0.f;
    #pragma unroll
    for (int s = 0; s < 8; s++) { pv[s] = expf(ev[s] - mx); sum += pv[s]; }
    #pragma unroll
    for (int off = 32; off; off >>= 1) sum += __shfl_xor(sum, off);
    __syncthreads();
    if (lane == 0) scratch[wid] = sum;
    __syncthreads();
    if (tid == 0) {
        float s2 = 0.f;
        for (int i = 0; i < 16; i++) s2 += scratch[i];
        scratch[21] = s2;
    }
    __syncthreads();
    float inv = 1.0f / scratch[21];
    #pragma unroll
    for (int s = 0; s < 8; s++) {
        int l = tid + s*1024;
        float sm = pv[s] * inv;
        sim[(size_t)b*L_ + l] = sm;
        kw[(size_t)b*L_ + l] =
            ((unsigned long long)__float_as_uint(sm) << 32) | (unsigned)(0xFFFFFFFFu - l);
    }
}

// ---------------- sort 1024-element chunks descending (bitonic in LDS) ----------------
__global__ __launch_bounds__(256) void sort1k_kernel(unsigned long long* __restrict__ keys)
{
    __shared__ unsigned long long k[1024];
    size_t base = (size_t)blockIdx.x * 1024;
    int tid = threadIdx.x;
    #pragma unroll
    for (int s = 0; s < 4; s++) k[tid + s*256] = keys[base + tid + s*256];
    __syncthreads();
    for (int ksz = 2; ksz <= 1024; ksz <<= 1) {
        for (int j = ksz >> 1; j > 0; j >>= 1) {
            #pragma unroll
            for (int s = 0; s < 2; s++) {
                int p = tid + s*256;                       // pair 0..511
                int i = ((p & ~(j-1)) << 1) | (p & (j-1)); // bit j clear
                int ix = i | j;
                unsigned long long a = k[i], c = k[ix];
                bool desc = ((i & ksz) == 0);
                if (desc ? (a < c) : (a > c)) { k[i] = c; k[ix] = a; }
            }
            __syncthreads();
        }
    }
    #pragma unroll
    for (int s = 0; s < 4; s++) keys[base + tid + s*256] = k[tid + s*256];
}

// ---------------- merge pass: pairs of desc runs (distinct keys) via merge-path ----------------
__global__ __launch_bounds__(256) void merge_kernel(
    const unsigned long long* __restrict__ src, unsigned long long* __restrict__ dst, int run)
{
    size_t base = (size_t)blockIdx.x * 2 * run;
    const unsigned long long* A = src + base;
    const unsigned long long* Bv = src + base + run;
    unsigned long long* D = dst + base;
    int per = (2*run) >> 8;                    // outputs per thread
    int p0 = threadIdx.x * per;
    int lo = (p0 > run) ? (p0 - run) : 0;
    int hi = (p0 < run) ? p0 : run;
    while (lo < hi) {
        int mid = (lo + hi) >> 1;
        if (A[mid] >= Bv[p0 - 1 - mid]) lo = mid + 1; else hi = mid;
    }
    int a = lo, bq = p0 - lo;
    for (int q = 0; q < per; q++) {
        unsigned long long va = (a < run) ? A[a] : 0ULL;
        unsigned long long vb = (bq < run) ? Bv[bq] : 0ULL;
        bool takeA = (bq >= run) || ((a < run) && (va > vb));
        D[p0 + q] = takeA ? va : vb;
        if (takeA) a++; else bq++;
    }
}

// ---------------- emit top-KTOP indices per batch ----------------
__global__ void emit_idx_kernel(const unsigned long long* __restrict__ kw, int* __restrict__ idxo)
{
    int b = blockIdx.x;
    for (int t = threadIdx.x; t < KTOP; t += blockDim.x)
        idxo[b*KTOP + t] = (int)(0xFFFFFFFFu - (unsigned)(kw[(size_t)b*L_ + t] & 0xFFFFFFFFu));
}

// ---------------- y: tiled over 32 consecutive t with 51-row LDS window ----------------
#define TT 32
__global__ __launch_bounds__(256) void y_kernel(const float* __restrict__ xp,
    const int* __restrict__ idx, const float* __restrict__ conv_w,
    const float* __restrict__ cf, float* __restrict__ y)
{
    __shared__ float rows[(TT + JT - 1) * C_];   // 51 rows x 1KB = 51KB
    const int b = blockIdx.y;
    const int t0 = blockIdx.x * TT;
    const int tid = threadIdx.x;
    const int c4 = (tid & 63) * 4;
    const int tg = tid >> 6;
    const int* idxb = idx + b*KTOP;

    for (int s = tid; s < (TT + JT - 1) * 64; s += 256) {
        int r = s >> 6, cq = (s & 63) * 4;
        int gi = t0 - (JT - 1) + r;
        float4 v = make_float4(0.f, 0.f, 0.f, 0.f);
        if (gi >= 0 && gi < KTOP) {
            int l = idxb[gi];
            v = *(const float4*)&xp[((size_t)b*L_ + l)*C_ + cq];
        }
        *(float4*)&rows[r*C_ + cq] = v;
    }
    float4 cfr[JT];
    #pragma unroll
    for (int j = 0; j < JT; j++) cfr[j] = *(const float4*)&cf[j*C_ + c4];
    float4 cw = *(const float4*)&conv_w[c4];
    __syncthreads();

    #pragma unroll
    for (int u = 0; u < TT/4; u++) {
        int tl = tg + u*4;
        int t = t0 + tl;
        if (t < KTOP) {
            float4 acc = make_float4(0.f, 0.f, 0.f, 0.f);
            #pragma unroll
            for (int j = 0; j < JT; j++) {
                const float4 v = *(const float4*)&rows[(tl + JT - 1 - j)*C_ + c4];
                acc.x = fmaf(cfr[j].x, v.x, acc.x);
                acc.y = fmaf(cfr[j].y, v.y, acc.y);
                acc.z = fmaf(cfr[j].z, v.z, acc.z);
                acc.w = fmaf(cfr[j].w, v.w, acc.w);
            }
            acc.x *= cw.x; acc.y *= cw.y; acc.z *= cw.z; acc.w *= cw.w;
            *(float4*)&y[((size_t)b*KTOP + t)*C_ + c4] = acc;
        }
    }
}

// ---------------- GEMM2 + scatter epilogue: out[b,l,:] = x[b,l,:] + y@WoT + bo ----------------
__global__ __launch_bounds__(256, 2) void gemm2_kernel(
    const float* __restrict__ y, const float* __restrict__ WoT,
    const float* __restrict__ bo, const float* __restrict__ x,
    const int* __restrict__ idx, float* __restrict__ out0)
{
    __shared__ float As[128*32];
    __shared__ float Bs[32*256];
    const int tid = threadIdx.x;
    const int tn2 = tid & 31;
    const int tm2 = tid >> 5;
    const int m0 = blockIdx.x * 128;
    const int ar = tid >> 3;
    const int ak = (tid & 7) * 4;
    const int br = tid >> 6;
    const int bc = (tid & 63) * 4;

    float acc[16][8];
    #pragma unroll
    for (int i = 0; i < 16; i++)
        #pragma unroll
        for (int j = 0; j < 8; j++) acc[i][j] = 0.f;

    float4 xa[4], wb[8];
    #pragma unroll
    for (int it = 0; it < 4; it++) {
        int m = m0 + ar + it*32;
        xa[it] = (m < M2) ? *(const float4*)&y[(size_t)m*C_ + ak]
                          : make_float4(0.f, 0.f, 0.f, 0.f);
    }
    #pragma unroll
    for (int it = 0; it < 8; it++)
        wb[it] = *(const float4*)&WoT[(size_t)(br + it*4)*C_ + bc];

    for (int k0 = 0; k0 < C_; k0 += 32) {
        #pragma unroll
        for (int it = 0; it < 4; it++)
            *(float4*)&As[(ar + it*32)*32 + ak] = xa[it];
        #pragma unroll
        for (int it = 0; it < 8; it++)
            *(float4*)&Bs[(br + it*4)*256 + bc] = wb[it];
        __syncthreads();
        if (k0 + 32 < C_) {
            #pragma unroll
            for (int it = 0; it < 4; it++) {
                int m = m0 + ar + it*32;
                xa[it] = (m < M2) ? *(const float4*)&y[(size_t)m*C_ + k0 + 32 + ak]
                                  : make_float4(0.f, 0.f, 0.f, 0.f);
            }
            #pragma unroll
            for (int it = 0; it < 8; it++)
                wb[it] = *(const float4*)&WoT[(size_t)(k0 + 32 + br + it*4)*C_ + bc];
        }
        #pragma unroll 2
        for (int kk = 0; kk < 32; kk++) {
            float4 b0 = *(const float4*)&Bs[kk*256 + tn2*4];
            float4 b1 = *(const float4*)&Bs[kk*256 + tn2*4 + 128];
            #pragma unroll
            for (int i = 0; i < 16; i++) {
                float a = As[(tm2*16 + i)*32 + kk];
                acc[i][0] = fmaf(a, b0.x, acc[i][0]);
                acc[i][1] = fmaf(a, b0.y, acc[i][1]);
                acc[i][2] = fmaf(a, b0.z, acc[i][2]);
                acc[i][3] = fmaf(a, b0.w, acc[i][3]);
                acc[i][4] = fmaf(a, b1.x, acc[i][4]);
                acc[i][5] = fmaf(a, b1.y, acc[i][5]);
                acc[i][6] = fmaf(a, b1.z, acc[i][6]);
                acc[i][7] = fmaf(a, b1.w, acc[i][7]);
            }
        }
        __syncthreads();
    }
    float4 bo0 = *(const float4*)&bo[tn2*4];
    float4 bo1 = *(const float4*)&bo[tn2*4 + 128];
    #pragma unroll
    for (int i = 0; i < 16; i++) {
        int m = m0 + tm2*16 + i;
        if (m < M2) {
            int b = m / KTOP, t = m - b*KTOP;
            int l = idx[b*KTOP + t];
            size_t base = ((size_t)b*L_ + l)*C_;
            float4 x0 = *(const float4*)&x[base + tn2*4];
            float4 x1 = *(const float4*)&x[base + tn2*4 + 128];
            float4 o0 = make_float4(acc[i][0]+bo0.x+x0.x, acc[i][1]+bo0.y+x0.y,
                                    acc[i][2]+bo0.z+x0.z, acc[i][3]+bo0.w+x0.w);
            float4 o1 = make_float4(acc[i][4]+bo1.x+x1.x, acc[i][5]+bo1.y+x1.y,
                                    acc[i][6]+bo1.z+x1.z, acc[i][7]+bo1.w+x1.w);
            *(float4*)&out0[base + tn2*4]       = o0;
            *(float4*)&out0[base + tn2*4 + 128] = o1;
        }
    }
}

extern "C" void kernel_launch(void* const* d_in, const int* in_sizes, int n_in,
                              void* d_out, int out_size, void* d_ws, size_t ws_size,
                              hipStream_t stream)
{
    const float* x      = (const float*)d_in[0];
    const float* alpha  = (const float*)d_in[1];
    const float* dyt_w  = (const float*)d_in[2];
    const float* dyt_b  = (const float*)d_in[3];
    const float* Wi     = (const float*)d_in[4];
    const float* bi     = (const float*)d_in[5];
    const float* conv_w = (const float*)d_in[6];
    const float* A      = (const float*)d_in[7];
    const float* Bp     = (const float*)d_in[8];
    const float* Cp     = (const float*)d_in[9];
    const float* Wo     = (const float*)d_in[10];
    const float* bo     = (const float*)d_in[11];

    float* ws  = (float*)d_ws;
    float* xp  = ws + XP_OFF;
    float* yb  = ws + Y_OFF;
    float* e   = ws + E_OFF;
    float* cn  = ws + CN_OFF;
    float* cf  = ws + CF_OFF;
    int*   idx = (int*)(ws + IDX_OFF);
    float* WiT = ws + WIT_OFF;
    float* WoT = ws + WOT_OFF;
    // key buffers alias yb (dead until y_kernel): 2 x 1MB
    unsigned long long* kw1 = (unsigned long long*)(ws + Y_OFF);
    unsigned long long* kw2 = kw1 + (size_t)B_*L_;

    float* out0 = (float*)d_out;
    float* sim  = out0 + (size_t)M1*C_;

    transpose_kernel<<<dim3(8,8,2), dim3(32,8), 0, stream>>>(Wi, Wo, WiT, WoT);
    coef_kernel<<<1, 256, 0, stream>>>(A, Bp, Cp, cf);
    center2_kernel<<<B_, 256, 0, stream>>>(x, WiT, bi, alpha, dyt_w, dyt_b, cn);
    gemm1_kernel<<<M1/128, 256, 0, stream>>>(x, WiT, bi, alpha, dyt_w, dyt_b, cn, xp, e, out0);
    softmax_kernel<<<B_, 1024, 0, stream>>>(e, sim, kw1);
    sort1k_kernel<<<B_*L_/1024, 256, 0, stream>>>(kw1);
    merge_kernel<<<B_*L_/2048, 256, 0, stream>>>(kw1, kw2, 1024);
    merge_kernel<<<B_*L_/4096, 256, 0, stream>>>(kw2, kw1, 2048);
    merge_kernel<<<B_*L_/8192, 256, 0, stream>>>(kw1, kw2, 4096);
    emit_idx_kernel<<<B_, 256, 0, stream>>>(kw2, idx);
    y_kernel<<<dim3((KTOP + TT - 1)/TT, B_), 256, 0, stream>>>(xp, idx, conv_w, cf, yb);
    gemm2_kernel<<<(M2 + 127)/128, 256, 0, stream>>>(yb, WoT, bo, x, idx, out0);
}